// Round 6
// baseline (825.128 us; speedup 1.0000x reference)
//
#include <hip/hip_runtime.h>
#include <hip/hip_bf16.h>
#include <hip/hip_fp16.h>
#include <cstdio>

#define N_NODES 10000
#define M_NODEP 10112            // 10000 padded to 79*128
#define N_EDGES 50000
#define M_EDGEP 50048            // 50000 padded to 391*128
#define E_AUG   60000
#define E_AUGP  60032            // 469*128
#define ED      16
#define BI_OUT  272
#define KP      288              // 272 padded to 9*32

typedef __attribute__((ext_vector_type(8))) short s16x8;   // 8 bf16 (4 VGPRs)
typedef __attribute__((ext_vector_type(4))) short s16x4;
typedef __attribute__((ext_vector_type(8))) _Float16 h16x8;
typedef __attribute__((ext_vector_type(4))) _Float16 h16x4;
typedef __attribute__((ext_vector_type(4))) float f32x4;

__device__ inline void stc(float* p, float v){ *p = v; }
__device__ inline void stc(__hip_bfloat16* p, float v){ *p = __float2bfloat16(v); }
__device__ inline void stc(__half* p, float v){ *p = __float2half(v); }
__device__ inline float bf2f(short s){ return __uint_as_float(((unsigned)(unsigned short)s) << 16); }
__device__ inline short f2bf(float f){ __hip_bfloat16 h = __float2bfloat16(f); return *(short*)&h; }

// async global->LDS, 16 B per lane; LDS dest is wave-uniform base (lane*16 implicit)
__device__ __forceinline__ void gl2lds16(const void* g, void* l){
  __builtin_amdgcn_global_load_lds((const __attribute__((address_space(1))) void*)g,
                                   (__attribute__((address_space(3))) void*)l, 16, 0, 0);
}

// ---------- mean edge_attr per dst (self-loop fill) ----------
__global__ void edge_attr_sum_k(const float* __restrict__ ea, const int* __restrict__ ei,
                                float* __restrict__ meanat, float* __restrict__ cntF){
  int t = blockIdx.x*256 + threadIdx.x;
  if (t >= N_EDGES*ED) return;
  int e = t >> 4, j = t & 15;
  int dst = ei[N_EDGES + e];
  atomicAdd(&meanat[dst*ED + j], ea[t]);
  if (j == 0) atomicAdd(&cntF[dst], 1.0f);
}

__global__ void mean_div_k(float* __restrict__ meanat, const float* __restrict__ cntF){
  int t = blockIdx.x*256 + threadIdx.x;
  if (t >= N_NODES*ED) return;
  meanat[t] /= fmaxf(cntF[t>>4], 1.0f);
}

// ---------- CSR build ----------
__global__ void scan_k(const float* __restrict__ cntF, int* __restrict__ rowptr){
  __shared__ int s[1024];
  int tid = threadIdx.x;
  int loc[10]; int sum = 0;
  #pragma unroll
  for (int k = 0; k < 10; ++k){
    int i = tid*10 + k;
    int v = (i < N_NODES) ? ((int)cntF[i] + 1) : 0;   // +1 self loop
    loc[k] = sum; sum += v;
  }
  s[tid] = sum; __syncthreads();
  for (int off = 1; off < 1024; off <<= 1){
    int t2 = (tid >= off) ? s[tid-off] : 0;
    __syncthreads();
    s[tid] += t2;
    __syncthreads();
  }
  int pre = s[tid] - sum;
  #pragma unroll
  for (int k = 0; k < 10; ++k){
    int i = tid*10 + k;
    if (i < N_NODES) rowptr[i] = pre + loc[k];
  }
  if (tid == 1023) rowptr[N_NODES] = s[1023];
}

__global__ void scatter_k(const int* __restrict__ ei, const int* __restrict__ rowptr,
                          int* __restrict__ fill, int* __restrict__ csr){
  int e = blockIdx.x*256 + threadIdx.x;
  if (e >= E_AUG) return;
  int dst = (e < N_EDGES) ? ei[N_EDGES+e] : (e - N_EDGES);
  int pos = rowptr[dst] + atomicAdd(&fill[dst], 1);
  csr[pos] = e;
}

// ---------- MFMA bf16 GEMM: C[M,N] = A[M,K] @ B^T[N,K]^T ----------
// LDS layout: chunk(16B) index = rowblock*128 + quad*32 + (row&31); fragment
// ds_read_b128 start bank = 4*(row&31)%32 -> exact 2-way across 16 lanes (free).
template<typename TC, bool BIAS, bool RELU>
__global__ __launch_bounds__(256)
void mfma_gemm_k(const __hip_bfloat16* __restrict__ A, const __hip_bfloat16* __restrict__ Bt,
                 TC* __restrict__ C, const float* __restrict__ bias,
                 int Mstore, int K, int lda, int ldb, int ldc){
  __shared__ __align__(16) __hip_bfloat16 Asm[4096];
  __shared__ __align__(16) __hip_bfloat16 Bsm[4096];
  const int tid = threadIdx.x;
  const int lane = tid & 63, wave = tid >> 6;
  const int wm = (wave >> 1) * 64, wn = (wave & 1) * 64;
  const int m0 = blockIdx.x * 128, n0 = blockIdx.y * 128;
  const int quad = lane >> 4, r16 = lane & 15;

  f32x4 acc[4][4];
  #pragma unroll
  for (int i = 0; i < 4; ++i)
    #pragma unroll
    for (int j = 0; j < 4; ++j)
      acc[i][j] = (f32x4){0.f, 0.f, 0.f, 0.f};

  // staging: wave w covers rows [w*32, w*32+32); lane l = qh*32 + r supplies
  // global (row = w*32+r, kcols (q0+qh)*8..+7) -> LDS chunk w*128 + (q0+qh)*32 + r
  const int r_l = lane & 31, qh = lane >> 5;
  const __hip_bfloat16* ga = &A[(size_t)(m0 + wave*32 + r_l)*lda + qh*8];
  const __hip_bfloat16* gb = &Bt[(size_t)(n0 + wave*32 + r_l)*ldb + qh*8];
  __hip_bfloat16* lA0 = &Asm[wave*1024];
  __hip_bfloat16* lA1 = &Asm[wave*1024 + 512];
  __hip_bfloat16* lB0 = &Bsm[wave*1024];
  __hip_bfloat16* lB1 = &Bsm[wave*1024 + 512];

  for (int k0 = 0; k0 < K; k0 += 32){
    gl2lds16(ga + k0,      lA0);
    gl2lds16(ga + k0 + 16, lA1);
    gl2lds16(gb + k0,      lB0);
    gl2lds16(gb + k0 + 16, lB1);
    __syncthreads();
    s16x8 af[4], bf[4];
    #pragma unroll
    for (int i = 0; i < 4; ++i){
      int row = wm + i*16 + r16;
      af[i] = *(const s16x8*)&Asm[((row >> 5) << 10) + (quad << 8) + ((row & 31) << 3)];
    }
    #pragma unroll
    for (int j = 0; j < 4; ++j){
      int row = wn + j*16 + r16;
      bf[j] = *(const s16x8*)&Bsm[((row >> 5) << 10) + (quad << 8) + ((row & 31) << 3)];
    }
    #pragma unroll
    for (int i = 0; i < 4; ++i)
      #pragma unroll
      for (int j = 0; j < 4; ++j)
        acc[i][j] = __builtin_amdgcn_mfma_f32_16x16x32_bf16(af[i], bf[j], acc[i][j], 0, 0, 0);
    __syncthreads();
  }
  #pragma unroll
  for (int i = 0; i < 4; ++i){
    #pragma unroll
    for (int reg = 0; reg < 4; ++reg){
      int gr = m0 + wm + i*16 + quad*4 + reg;
      if (gr >= Mstore) continue;
      #pragma unroll
      for (int j = 0; j < 4; ++j){
        int gc = n0 + wn + j*16 + r16;
        float v = acc[i][j][reg];
        if (BIAS) v += bias[gc];
        if (RELU) v = fmaxf(v, 0.f);
        stc(&C[(size_t)gr*ldc + gc], v);
      }
    }
  }
}

// ---------- prep kernels ----------
// WT rows [0,dn) = Wl^T, rows [dn,2dn) = Wr^T  (ldb = din)
__global__ void transpose_wlr_k(const float* __restrict__ Wl, const float* __restrict__ Wr,
                                __hip_bfloat16* __restrict__ WT, int din, int dn){
  int t = blockIdx.x*256 + threadIdx.x;
  if (t >= 2*din*dn) return;
  int half = t / (din*dn);
  int r = t - half*din*dn;
  int i = r / dn, j = r - i*dn;
  const float* W = half ? Wr : Wl;
  WT[(size_t)(half*dn + j)*din + i] = __float2bfloat16(W[r]);
}

__global__ void cast_h_k(const float* __restrict__ h, __hip_bfloat16* __restrict__ hb, int K){
  int t = blockIdx.x*256 + threadIdx.x;
  if (t >= M_NODEP*K) return;
  int r = t / K;
  hb[t] = (r < N_NODES) ? __float2bfloat16(h[t]) : __float2bfloat16(0.f);
}

// ea_aug -> bf16 [E_AUGP x 32] (K padded 16->32)
__global__ void cast_ea_k(const float* __restrict__ ea, const float* __restrict__ meanat,
                          __hip_bfloat16* __restrict__ eab){
  int t = blockIdx.x*256 + threadIdx.x;
  if (t >= E_AUGP*32) return;
  int e = t >> 5, j = t & 31;
  float v = 0.f;
  if (j < 16){
    if (e < N_EDGES) v = ea[(size_t)e*ED + j];
    else if (e < E_AUG) v = meanat[(size_t)(e - N_EDGES)*ED + j];
  }
  eab[t] = __float2bfloat16(v);
}

// We[16 x dout] -> WeT[dout x 32] bf16 (B^T, K padded)
__global__ void weT_k(const float* __restrict__ We, __hip_bfloat16* __restrict__ WeT, int dout){
  int t = blockIdx.x*256 + threadIdx.x;
  if (t >= dout*32) return;
  int n = t >> 5, k = t & 31;
  WeT[t] = __float2bfloat16((k < 16) ? We[(size_t)k*dout + n] : 0.f);
}

// Wbi[k<272][i<1024][j<16] -> WtAll: per chunk c, rows base[c]+[0,cw)=L, +[cw,2cw)=R; col = i&511
__global__ void wbi_transpose_k(const float* __restrict__ Wbi, __hip_bfloat16* __restrict__ WtAll){
  int t = blockIdx.x*256 + threadIdx.x;
  if (t >= BI_OUT*1024*ED) return;
  int k = t >> 14, r = t & 16383;
  int i = r >> 4, j = r & 15;
  int c = (k < 96) ? 0 : ((k < 192) ? 1 : 2);
  int kb = c*96;
  int base = c*3072;
  int cw = (c < 2) ? 1536 : 1280;
  int row = base + ((i >= 512) ? cw : 0) + (k - kb)*16 + j;
  WtAll[(size_t)row*512 + (i & 511)] = __float2bfloat16(Wbi[t]);
}

__global__ void prep_mlp_k(const float* __restrict__ Wm1, const float* __restrict__ bm1,
                           const float* __restrict__ Wm2, const float* __restrict__ bm2,
                           __hip_bfloat16* __restrict__ Wm1T, __hip_bfloat16* __restrict__ Wm2T,
                           float* __restrict__ bm1p, float* __restrict__ bm2p){
  int t = blockIdx.x*256 + threadIdx.x;
  if (t < 384*KP){
    int n = t / KP, k = t - n*KP;
    Wm1T[t] = __float2bfloat16((n < BI_OUT && k < BI_OUT) ? Wm1[(size_t)k*BI_OUT + n] : 0.f);
  }
  if (t < 128*KP){
    int n = t / KP, k = t - n*KP;
    Wm2T[t] = __float2bfloat16((n < 32 && k < BI_OUT) ? Wm2[(size_t)k*32 + n] : 0.f);
  }
  if (t < 384) bm1p[t] = (t < BI_OUT) ? bm1[t] : 0.f;
  if (t < 128) bm2p[t] = (t < 32) ? bm2[t] : 0.f;
}

// ---------- fused GAT: one-pass online softmax + aggregate, 1 wave per dst ----------
// d-indexing is lane-blocked: d = lane*NI + i  (order-independent sums)
template<int DOUT, bool RELU>
__global__ __launch_bounds__(256)
void gat_fused_k(const __hip_bfloat16* __restrict__ XLXR, const __half* __restrict__ EE,
                 const int* __restrict__ ei, const int* __restrict__ rowptr,
                 const int* __restrict__ csr, const float* __restrict__ att,
                 const float* __restrict__ b, __hip_bfloat16* __restrict__ hb){
  constexpr int NI = DOUT/64;
  constexpr int W2 = 2*DOUT;
  int wave = threadIdx.x >> 6, lane = threadIdx.x & 63;
  int n = blockIdx.x*4 + wave;
  if (n >= N_NODES) return;
  int r0 = rowptr[n], r1 = rowptr[n+1];
  // prefetch segment indices into lane registers
  int pp = r0 + lane;
  int e_l = 0, s_l = 0;
  if (pp < r1){
    e_l = csr[pp];
    s_l = (e_l < N_EDGES) ? ei[e_l] : (e_l - N_EDGES);
  }
  float xr[NI], at[NI], acc[NI];
  #pragma unroll
  for (int i = 0; i < NI; ++i){
    int d = lane*NI + i;
    xr[i]  = bf2f(((const short*)XLXR)[(size_t)n*W2 + DOUT + d]);
    at[i]  = att[d];
    acc[i] = 0.f;
  }
  float mrun = -1e30f, den = 0.f;
  for (int p = r0; p < r1; ++p){
    int idx = p - r0;
    int e, src;
    if (idx < 64){ e = __shfl(e_l, idx, 64); src = __shfl(s_l, idx, 64); }
    else { e = csr[p]; src = (e < N_EDGES) ? ei[e] : (e - N_EDGES); }
    const short* xlp = (const short*)XLXR + (size_t)src*W2 + lane*NI;
    const _Float16* eep = (const _Float16*)EE + (size_t)e*DOUT + lane*NI;
    float xl[NI];
    float a = 0.f;
    if constexpr (NI == 8){
      s16x8 xv = *(const s16x8*)xlp;
      h16x8 ev = *(const h16x8*)eep;
      #pragma unroll
      for (int i = 0; i < 8; ++i){
        xl[i] = bf2f(xv[i]);
        float v = xl[i] + xr[i] + (float)ev[i];
        v = (v > 0.f) ? v : 0.2f*v;
        a += at[i]*v;
      }
    } else {
      s16x4 xv = *(const s16x4*)xlp;
      h16x4 ev = *(const h16x4*)eep;
      #pragma unroll
      for (int i = 0; i < 4; ++i){
        xl[i] = bf2f(xv[i]);
        float v = xl[i] + xr[i] + (float)ev[i];
        v = (v > 0.f) ? v : 0.2f*v;
        a += at[i]*v;
      }
    }
    #pragma unroll
    for (int off = 32; off; off >>= 1) a += __shfl_down(a, off, 64);
    a = __shfl(a, 0, 64);
    float mnew = fmaxf(mrun, a);
    float scale = __expf(mrun - mnew);
    float w = __expf(a - mnew);
    den = den*scale + w;
    #pragma unroll
    for (int i = 0; i < NI; ++i) acc[i] = acc[i]*scale + w*xl[i];
    mrun = mnew;
  }
  float dinv = 1.0f / fmaxf(den, 1e-16f);
  if constexpr (NI == 8){
    s16x8 o;
    #pragma unroll
    for (int i = 0; i < 8; ++i){
      float v = b[lane*8 + i] + acc[i]*dinv;
      o[i] = f2bf(RELU ? fmaxf(v, 0.f) : v);
    }
    *(s16x8*)((short*)hb + (size_t)n*DOUT + lane*8) = o;
  } else {
    s16x4 o;
    #pragma unroll
    for (int i = 0; i < 4; ++i){
      float v = b[lane*4 + i] + acc[i]*dinv;
      o[i] = f2bf(RELU ? fmaxf(v, 0.f) : v);
    }
    *(s16x4*)((short*)hb + (size_t)n*DOUT + lane*4) = o;
  }
}

// ---------- per-edge bilinear contraction over j (P interleaved: [node x 2cw]) ----------
__global__ void bi_k(const __hip_bfloat16* __restrict__ P, const float* __restrict__ ea,
                     const int* __restrict__ ei, const float* __restrict__ bbi,
                     __hip_bfloat16* __restrict__ bi, int kb, int kcnt){
  int cw = kcnt*ED, w2 = 2*cw;
  int g = blockIdx.x*256 + threadIdx.x;
  if (g >= N_EDGES*kcnt) return;
  int n = g / kcnt, k = g - n*kcnt;
  int src = ei[n], dst = ei[N_EDGES+n];
  const __hip_bfloat16* pl = P + (size_t)src*w2 + k*ED;
  const __hip_bfloat16* pr = P + (size_t)dst*w2 + cw + k*ED;
  const float* eap = ea + (size_t)n*ED;
  float s = 0.f;
  #pragma unroll
  for (int j = 0; j < ED; ++j)
    s += eap[j]*(__bfloat162float(pl[j]) + __bfloat162float(pr[j]));
  int kg = kb + k;
  bi[(size_t)n*KP + kg] = __float2bfloat16(s + bbi[kg]);
}

// ---------- final tiny GEMV + sigmoid ----------
__global__ void out_k(const __hip_bfloat16* __restrict__ m2, const float* __restrict__ Wm3,
                      const float* __restrict__ bm3, float* __restrict__ out){
  int n = blockIdx.x*256 + threadIdx.x;
  if (n >= N_EDGES) return;
  float acc = bm3[0];
  #pragma unroll
  for (int j = 0; j < 32; ++j) acc += __bfloat162float(m2[(size_t)n*128 + j])*Wm3[j];
  out[n] = 1.0f/(1.0f + __expf(-acc));
}

extern "C" void kernel_launch(void* const* d_in, const int* in_sizes, int n_in,
                              void* d_out, int out_size, void* d_ws, size_t ws_size,
                              hipStream_t stream) {
  const float* x   = (const float*)d_in[0];
  const float* ea  = (const float*)d_in[1];
  const int*   ei  = (const int*)d_in[2];
  const float* Wl[4]  = {(const float*)d_in[3],(const float*)d_in[8],(const float*)d_in[13],(const float*)d_in[18]};
  const float* Wr[4]  = {(const float*)d_in[4],(const float*)d_in[9],(const float*)d_in[14],(const float*)d_in[19]};
  const float* We[4]  = {(const float*)d_in[5],(const float*)d_in[10],(const float*)d_in[15],(const float*)d_in[20]};
  const float* att[4] = {(const float*)d_in[6],(const float*)d_in[11],(const float*)d_in[16],(const float*)d_in[21]};
  const float* bia[4] = {(const float*)d_in[7],(const float*)d_in[12],(const float*)d_in[17],(const float*)d_in[22]};
  const float* Wbi = (const float*)d_in[23];
  const float* bbi = (const float*)d_in[24];
  const float* Wm1 = (const float*)d_in[25];
  const float* bm1 = (const float*)d_in[26];
  const float* Wm2 = (const float*)d_in[27];
  const float* bm2 = (const float*)d_in[28];
  const float* Wm3 = (const float*)d_in[29];
  const float* bm3 = (const float*)d_in[30];
  float* out = (float*)d_out;

  char* ws = (char*)d_ws;
  size_t off = 0;
  auto alloc = [&](size_t b){ off = (off + 255) & ~(size_t)255; size_t o = off; off += b; return o; };
  size_t o_bi   = alloc((size_t)M_EDGEP*KP*2);           // 28.83 MB
  size_t o_XLXR = alloc((size_t)M_NODEP*1024*2);         // 20.71 MB
  size_t o_hb   = alloc((size_t)M_NODEP*512*2);          // 10.35 MB
  size_t o_eab  = alloc((size_t)E_AUGP*32*2);            // 3.84 MB
  size_t o_WT   = alloc((size_t)1024*512*2);             // 1.05 MB
  size_t o_WtA  = alloc((size_t)8704*512*2);             // 8.91 MB
  size_t o_WeT  = alloc((size_t)512*32*2);
  size_t o_EEP  = alloc((size_t)61440000);               // EE | P-chunk | m1,m2
  size_t o_Wm1T = alloc((size_t)384*KP*2);
  size_t o_Wm2T = alloc((size_t)128*KP*2);
  size_t o_bm1p = alloc(384*4);
  size_t o_bm2p = alloc(128*4);
  size_t o_ma   = alloc((size_t)N_NODES*ED*4);
  size_t o_cnt  = alloc(40000);
  size_t o_rp   = alloc(40004);
  size_t o_fill = alloc(40000);
  size_t o_csr  = alloc(240000);
  if (off > ws_size){
    fprintf(stderr, "kernel_launch: workspace too small: need %zu have %zu\n", off, ws_size);
    return;
  }

  float* meanat = (float*)(ws + o_ma);
  float* cntF   = (float*)(ws + o_cnt);
  int*   rowptr = (int*)(ws + o_rp);
  int*   fill   = (int*)(ws + o_fill);
  int*   csr    = (int*)(ws + o_csr);
  __hip_bfloat16* XLXR = (__hip_bfloat16*)(ws + o_XLXR);
  __hip_bfloat16* hb   = (__hip_bfloat16*)(ws + o_hb);
  __hip_bfloat16* eab  = (__hip_bfloat16*)(ws + o_eab);
  __hip_bfloat16* WT   = (__hip_bfloat16*)(ws + o_WT);
  __hip_bfloat16* WtA  = (__hip_bfloat16*)(ws + o_WtA);
  __hip_bfloat16* WeT  = (__hip_bfloat16*)(ws + o_WeT);
  __half*        EE    = (__half*)(ws + o_EEP);
  __hip_bfloat16* P    = (__hip_bfloat16*)(ws + o_EEP);
  __hip_bfloat16* Wm1T = (__hip_bfloat16*)(ws + o_Wm1T);
  __hip_bfloat16* Wm2T = (__hip_bfloat16*)(ws + o_Wm2T);
  float* bm1p = (float*)(ws + o_bm1p);
  float* bm2p = (float*)(ws + o_bm2p);
  __hip_bfloat16* bi = (__hip_bfloat16*)(ws + o_bi);
  __hip_bfloat16* m1 = (__hip_bfloat16*)(ws + o_EEP);
  __hip_bfloat16* m2 = (__hip_bfloat16*)(ws + o_EEP + 40000000);

  // mean_attr + CSR build
  hipMemsetAsync(ws + o_ma, 0, (o_cnt - o_ma) + 40000, stream);
  hipMemsetAsync(ws + o_fill, 0, 40000, stream);
  edge_attr_sum_k<<<3125, 256, 0, stream>>>(ea, ei, meanat, cntF);
  mean_div_k<<<625, 256, 0, stream>>>(meanat, cntF);
  scan_k<<<1, 1024, 0, stream>>>(cntF, rowptr);
  scatter_k<<<235, 256, 0, stream>>>(ei, rowptr, fill, csr);

  // x cast (zeroes pad rows for layer 0), ea_aug cast. No hb/bi memsets:
  // pad garbage is finite and either ×0 weights or confined to unread pad rows.
  cast_h_k<<<(M_NODEP*32 + 255)/256, 256, 0, stream>>>(x, hb, 32);
  cast_ea_k<<<(E_AUGP*32 + 255)/256, 256, 0, stream>>>(ea, meanat, eab);

  const int dins[4]  = {32, 256, 512, 512};
  const int douts[4] = {256, 512, 512, 512};
  for (int L = 0; L < 4; ++L){
    int din = dins[L], dn = douts[L];
    transpose_wlr_k<<<(2*din*dn + 255)/256, 256, 0, stream>>>(Wl[L], Wr[L], WT, din, dn);
    weT_k<<<(dn*32 + 255)/256, 256, 0, stream>>>(We[L], WeT, dn);
    dim3 g1(M_NODEP/128, 2*dn/128);
    mfma_gemm_k<__hip_bfloat16,false,false><<<g1, 256, 0, stream>>>(
        hb, WT, XLXR, nullptr, N_NODES, din, din, din, 2*dn);
    dim3 ge(E_AUGP/128, dn/128);
    mfma_gemm_k<__half,false,false><<<ge, 256, 0, stream>>>(eab, WeT, EE, nullptr, E_AUG, 32, 32, 32, dn);
    if (dn == 256)
      gat_fused_k<256,true><<<2500, 256, 0, stream>>>(XLXR, EE, ei, rowptr, csr, att[L], bia[L], hb);
    else if (L == 3)
      gat_fused_k<512,false><<<2500, 256, 0, stream>>>(XLXR, EE, ei, rowptr, csr, att[L], bia[L], hb);
    else
      gat_fused_k<512,true><<<2500, 256, 0, stream>>>(XLXR, EE, ei, rowptr, csr, att[L], bia[L], hb);
  }
  // hb holds final node embeddings [M_NODEP x 512] bf16

  wbi_transpose_k<<<(BI_OUT*1024*ED + 255)/256, 256, 0, stream>>>(Wbi, WtA);

  // merged PL|PR GEMM per chunk: N = 2*cw, then bilinear
  const int kbs[3]   = {0, 96, 192};
  const int kcnts[3] = {96, 96, 80};
  const int bases[3] = {0, 3072, 6144};
  for (int c = 0; c < 3; ++c){
    int cw = kcnts[c]*ED, w2 = 2*cw;
    dim3 gp(M_NODEP/128, w2/128);
    mfma_gemm_k<__hip_bfloat16,false,false><<<gp, 256, 0, stream>>>(
        hb, WtA + (size_t)bases[c]*512, P, nullptr, N_NODES, 512, 512, 512, w2);
    bi_k<<<(N_EDGES*kcnts[c] + 255)/256, 256, 0, stream>>>(P, ea, ei, bbi, bi, kbs[c], kcnts[c]);
  }

  prep_mlp_k<<<(384*KP + 255)/256, 256, 0, stream>>>(Wm1, bm1, Wm2, bm2, Wm1T, Wm2T, bm1p, bm2p);
  dim3 gm1(M_EDGEP/128, 3);
  mfma_gemm_k<__hip_bfloat16,true,true><<<gm1, 256, 0, stream>>>(bi, Wm1T, m1, bm1p, M_EDGEP, KP, KP, KP, 384);
  dim3 gm2(M_EDGEP/128, 1);
  mfma_gemm_k<__hip_bfloat16,true,true><<<gm2, 256, 0, stream>>>(m1, Wm2T, m2, bm2p, M_EDGEP, KP, 384, KP, 128);
  out_k<<<(N_EDGES + 255)/256, 256, 0, stream>>>(m2, Wm3, bm3, out);
}

// Round 7
// 748.807 us; speedup vs baseline: 1.1019x; 1.1019x over previous
//
#include <hip/hip_runtime.h>
#include <hip/hip_bf16.h>
#include <hip/hip_fp16.h>
#include <cstdio>

#define N_NODES 10000
#define M_NODEP 10112            // 10000 padded to 79*128
#define N_EDGES 50000
#define M_EDGEP 50048            // 50000 padded to 391*128
#define E_AUG   60000
#define E_AUGP  60032            // 469*128
#define ED      16
#define BI_OUT  272
#define KP      288              // 272 padded to 9*32

typedef __attribute__((ext_vector_type(8))) short s16x8;   // 8 bf16 (4 VGPRs)
typedef __attribute__((ext_vector_type(4))) short s16x4;
typedef __attribute__((ext_vector_type(8))) _Float16 h16x8;
typedef __attribute__((ext_vector_type(4))) _Float16 h16x4;
typedef __attribute__((ext_vector_type(4))) float f32x4;

__device__ inline void stc(float* p, float v){ *p = v; }
__device__ inline void stc(__hip_bfloat16* p, float v){ *p = __float2bfloat16(v); }
__device__ inline void stc(__half* p, float v){ *p = __float2half(v); }
__device__ inline float bf2f(short s){ return __uint_as_float(((unsigned)(unsigned short)s) << 16); }
__device__ inline short f2bf(float f){ __hip_bfloat16 h = __float2bfloat16(f); return *(short*)&h; }

// async global->LDS, 16 B per lane; LDS dest is wave-uniform base (lane*16 implicit)
__device__ __forceinline__ void gl2lds16(const void* g, void* l){
  __builtin_amdgcn_global_load_lds((const __attribute__((address_space(1))) void*)g,
                                   (__attribute__((address_space(3))) void*)l, 16, 0, 0);
}

// ---------- mean edge_attr per dst (self-loop fill) ----------
__global__ void edge_attr_sum_k(const float* __restrict__ ea, const int* __restrict__ ei,
                                float* __restrict__ meanat, float* __restrict__ cntF){
  int t = blockIdx.x*256 + threadIdx.x;
  if (t >= N_EDGES*ED) return;
  int e = t >> 4, j = t & 15;
  int dst = ei[N_EDGES + e];
  atomicAdd(&meanat[dst*ED + j], ea[t]);
  if (j == 0) atomicAdd(&cntF[dst], 1.0f);
}

__global__ void mean_div_k(float* __restrict__ meanat, const float* __restrict__ cntF){
  int t = blockIdx.x*256 + threadIdx.x;
  if (t >= N_NODES*ED) return;
  meanat[t] /= fmaxf(cntF[t>>4], 1.0f);
}

// ---------- CSR build ----------
__global__ void scan_k(const float* __restrict__ cntF, int* __restrict__ rowptr){
  __shared__ int s[1024];
  int tid = threadIdx.x;
  int loc[10]; int sum = 0;
  #pragma unroll
  for (int k = 0; k < 10; ++k){
    int i = tid*10 + k;
    int v = (i < N_NODES) ? ((int)cntF[i] + 1) : 0;   // +1 self loop
    loc[k] = sum; sum += v;
  }
  s[tid] = sum; __syncthreads();
  for (int off = 1; off < 1024; off <<= 1){
    int t2 = (tid >= off) ? s[tid-off] : 0;
    __syncthreads();
    s[tid] += t2;
    __syncthreads();
  }
  int pre = s[tid] - sum;
  #pragma unroll
  for (int k = 0; k < 10; ++k){
    int i = tid*10 + k;
    if (i < N_NODES) rowptr[i] = pre + loc[k];
  }
  if (tid == 1023) rowptr[N_NODES] = s[1023];
}

__global__ void scatter_k(const int* __restrict__ ei, const int* __restrict__ rowptr,
                          int* __restrict__ fill, int* __restrict__ csr){
  int e = blockIdx.x*256 + threadIdx.x;
  if (e >= E_AUG) return;
  int dst = (e < N_EDGES) ? ei[N_EDGES+e] : (e - N_EDGES);
  int pos = rowptr[dst] + atomicAdd(&fill[dst], 1);
  csr[pos] = e;
}

// ---------- MFMA bf16 GEMM: C[M,N] = A[M,K] @ B^T[N,K]^T ----------
// LDS: element offset for (row,quad) = row*32 + ((quad + (row>>1))&3)*8.
// Fragment ds_read_b128 bank-starts cover {0,4,..,28} exactly 2x -> free.
// Staging: lane l of a 16-row region writes chunk l; global source is row
// R+l/4, quad=((l&3)-((row>>1)&3))&3 -> each row = one 64B segment (permuted).
template<typename TC, bool BIAS, bool RELU>
__global__ __launch_bounds__(256)
void mfma_gemm_k(const __hip_bfloat16* __restrict__ A, const __hip_bfloat16* __restrict__ Bt,
                 TC* __restrict__ C, const float* __restrict__ bias,
                 int Mstore, int K, int lda, int ldb, int ldc){
  __shared__ __align__(16) __hip_bfloat16 Asm[4096];
  __shared__ __align__(16) __hip_bfloat16 Bsm[4096];
  const int tid = threadIdx.x;
  const int lane = tid & 63, wave = tid >> 6;
  const int wm = (wave >> 1) * 64, wn = (wave & 1) * 64;
  const int m0 = blockIdx.x * 128, n0 = blockIdx.y * 128;
  const int quad = lane >> 4, r16 = lane & 15;

  f32x4 acc[4][4];
  #pragma unroll
  for (int i = 0; i < 4; ++i)
    #pragma unroll
    for (int j = 0; j < 4; ++j)
      acc[i][j] = (f32x4){0.f, 0.f, 0.f, 0.f};

  // staging: wave w covers rows [w*32, w*32+32) as two 16-row regions
  const int rl = lane >> 2, cq = lane & 3;
  const int row0 = wave*32 + rl;          // region 0 row
  const int qg = (cq - ((row0 >> 1) & 3)) & 3;   // same for row0+16
  const __hip_bfloat16* ga0 = &A[(size_t)(m0 + row0)*lda + qg*8];
  const __hip_bfloat16* ga1 = &A[(size_t)(m0 + row0 + 16)*lda + qg*8];
  const __hip_bfloat16* gb0 = &Bt[(size_t)(n0 + row0)*ldb + qg*8];
  const __hip_bfloat16* gb1 = &Bt[(size_t)(n0 + row0 + 16)*ldb + qg*8];
  __hip_bfloat16* lA0 = &Asm[(wave*32)*32];
  __hip_bfloat16* lA1 = &Asm[(wave*32 + 16)*32];
  __hip_bfloat16* lB0 = &Bsm[(wave*32)*32];
  __hip_bfloat16* lB1 = &Bsm[(wave*32 + 16)*32];

  for (int k0 = 0; k0 < K; k0 += 32){
    gl2lds16(ga0 + k0, lA0);
    gl2lds16(ga1 + k0, lA1);
    gl2lds16(gb0 + k0, lB0);
    gl2lds16(gb1 + k0, lB1);
    __syncthreads();
    s16x8 af[4], bf[4];
    #pragma unroll
    for (int i = 0; i < 4; ++i){
      int row = wm + i*16 + r16;
      af[i] = *(const s16x8*)&Asm[row*32 + (((quad + (row >> 1)) & 3) << 3)];
    }
    #pragma unroll
    for (int j = 0; j < 4; ++j){
      int row = wn + j*16 + r16;
      bf[j] = *(const s16x8*)&Bsm[row*32 + (((quad + (row >> 1)) & 3) << 3)];
    }
    #pragma unroll
    for (int i = 0; i < 4; ++i)
      #pragma unroll
      for (int j = 0; j < 4; ++j)
        acc[i][j] = __builtin_amdgcn_mfma_f32_16x16x32_bf16(af[i], bf[j], acc[i][j], 0, 0, 0);
    __syncthreads();
  }
  #pragma unroll
  for (int i = 0; i < 4; ++i){
    #pragma unroll
    for (int reg = 0; reg < 4; ++reg){
      int gr = m0 + wm + i*16 + quad*4 + reg;
      if (gr >= Mstore) continue;
      #pragma unroll
      for (int j = 0; j < 4; ++j){
        int gc = n0 + wn + j*16 + r16;
        float v = acc[i][j][reg];
        if (BIAS) v += bias[gc];
        if (RELU) v = fmaxf(v, 0.f);
        stc(&C[(size_t)gr*ldc + gc], v);
      }
    }
  }
}

// ---------- prep kernels ----------
// WT rows [0,dn) = Wl^T, rows [dn,2dn) = Wr^T  (ldb = din)
__global__ void transpose_wlr_k(const float* __restrict__ Wl, const float* __restrict__ Wr,
                                __hip_bfloat16* __restrict__ WT, int din, int dn){
  int t = blockIdx.x*256 + threadIdx.x;
  if (t >= 2*din*dn) return;
  int half = t / (din*dn);
  int r = t - half*din*dn;
  int i = r / dn, j = r - i*dn;
  const float* W = half ? Wr : Wl;
  WT[(size_t)(half*dn + j)*din + i] = __float2bfloat16(W[r]);
}

__global__ void cast_h_k(const float* __restrict__ h, __hip_bfloat16* __restrict__ hb, int K){
  int t = blockIdx.x*256 + threadIdx.x;
  if (t >= M_NODEP*K) return;
  int r = t / K;
  hb[t] = (r < N_NODES) ? __float2bfloat16(h[t]) : __float2bfloat16(0.f);
}

// ea_aug -> bf16 [E_AUGP x 32] (K padded 16->32)
__global__ void cast_ea_k(const float* __restrict__ ea, const float* __restrict__ meanat,
                          __hip_bfloat16* __restrict__ eab){
  int t = blockIdx.x*256 + threadIdx.x;
  if (t >= E_AUGP*32) return;
  int e = t >> 5, j = t & 31;
  float v = 0.f;
  if (j < 16){
    if (e < N_EDGES) v = ea[(size_t)e*ED + j];
    else if (e < E_AUG) v = meanat[(size_t)(e - N_EDGES)*ED + j];
  }
  eab[t] = __float2bfloat16(v);
}

// We[16 x dout] -> WeT[dout x 32] bf16 (B^T, K padded)
__global__ void weT_k(const float* __restrict__ We, __hip_bfloat16* __restrict__ WeT, int dout){
  int t = blockIdx.x*256 + threadIdx.x;
  if (t >= dout*32) return;
  int n = t >> 5, k = t & 31;
  WeT[t] = __float2bfloat16((k < 16) ? We[(size_t)k*dout + n] : 0.f);
}

// Wbi[k<272][i<1024][j<16] -> WtAll: per chunk c, rows base[c]+[0,cw)=L, +[cw,2cw)=R; col = i&511
__global__ void wbi_transpose_k(const float* __restrict__ Wbi, __hip_bfloat16* __restrict__ WtAll){
  int t = blockIdx.x*256 + threadIdx.x;
  if (t >= BI_OUT*1024*ED) return;
  int k = t >> 14, r = t & 16383;
  int i = r >> 4, j = r & 15;
  int c = (k < 96) ? 0 : ((k < 192) ? 1 : 2);
  int kb = c*96;
  int base = c*3072;
  int cw = (c < 2) ? 1536 : 1280;
  int row = base + ((i >= 512) ? cw : 0) + (k - kb)*16 + j;
  WtAll[(size_t)row*512 + (i & 511)] = __float2bfloat16(Wbi[t]);
}

__global__ void prep_mlp_k(const float* __restrict__ Wm1, const float* __restrict__ bm1,
                           const float* __restrict__ Wm2, const float* __restrict__ bm2,
                           __hip_bfloat16* __restrict__ Wm1T, __hip_bfloat16* __restrict__ Wm2T,
                           float* __restrict__ bm1p, float* __restrict__ bm2p){
  int t = blockIdx.x*256 + threadIdx.x;
  if (t < 384*KP){
    int n = t / KP, k = t - n*KP;
    Wm1T[t] = __float2bfloat16((n < BI_OUT && k < BI_OUT) ? Wm1[(size_t)k*BI_OUT + n] : 0.f);
  }
  if (t < 128*KP){
    int n = t / KP, k = t - n*KP;
    Wm2T[t] = __float2bfloat16((n < 32 && k < BI_OUT) ? Wm2[(size_t)k*32 + n] : 0.f);
  }
  if (t < 384) bm1p[t] = (t < BI_OUT) ? bm1[t] : 0.f;
  if (t < 128) bm2p[t] = (t < 32) ? bm2[t] : 0.f;
}

// ---------- fused GAT: one-pass online softmax + aggregate, 1 wave per dst ----------
// d-indexing is lane-blocked: d = lane*NI + i  (order-independent sums)
template<int DOUT, bool RELU>
__global__ __launch_bounds__(256)
void gat_fused_k(const __hip_bfloat16* __restrict__ XLXR, const __half* __restrict__ EE,
                 const int* __restrict__ ei, const int* __restrict__ rowptr,
                 const int* __restrict__ csr, const float* __restrict__ att,
                 const float* __restrict__ b, __hip_bfloat16* __restrict__ hb){
  constexpr int NI = DOUT/64;
  constexpr int W2 = 2*DOUT;
  int wave = threadIdx.x >> 6, lane = threadIdx.x & 63;
  int n = blockIdx.x*4 + wave;
  if (n >= N_NODES) return;
  int r0 = rowptr[n], r1 = rowptr[n+1];
  // prefetch segment indices into lane registers
  int pp = r0 + lane;
  int e_l = 0, s_l = 0;
  if (pp < r1){
    e_l = csr[pp];
    s_l = (e_l < N_EDGES) ? ei[e_l] : (e_l - N_EDGES);
  }
  float xr[NI], at[NI], acc[NI];
  #pragma unroll
  for (int i = 0; i < NI; ++i){
    int d = lane*NI + i;
    xr[i]  = bf2f(((const short*)XLXR)[(size_t)n*W2 + DOUT + d]);
    at[i]  = att[d];
    acc[i] = 0.f;
  }
  float mrun = -1e30f, den = 0.f;
  for (int p = r0; p < r1; ++p){
    int idx = p - r0;
    int e, src;
    if (idx < 64){ e = __shfl(e_l, idx, 64); src = __shfl(s_l, idx, 64); }
    else { e = csr[p]; src = (e < N_EDGES) ? ei[e] : (e - N_EDGES); }
    const short* xlp = (const short*)XLXR + (size_t)src*W2 + lane*NI;
    const _Float16* eep = (const _Float16*)EE + (size_t)e*DOUT + lane*NI;
    float xl[NI];
    float a = 0.f;
    if constexpr (NI == 8){
      s16x8 xv = *(const s16x8*)xlp;
      h16x8 ev = *(const h16x8*)eep;
      #pragma unroll
      for (int i = 0; i < 8; ++i){
        xl[i] = bf2f(xv[i]);
        float v = xl[i] + xr[i] + (float)ev[i];
        v = (v > 0.f) ? v : 0.2f*v;
        a += at[i]*v;
      }
    } else {
      s16x4 xv = *(const s16x4*)xlp;
      h16x4 ev = *(const h16x4*)eep;
      #pragma unroll
      for (int i = 0; i < 4; ++i){
        xl[i] = bf2f(xv[i]);
        float v = xl[i] + xr[i] + (float)ev[i];
        v = (v > 0.f) ? v : 0.2f*v;
        a += at[i]*v;
      }
    }
    #pragma unroll
    for (int off = 32; off; off >>= 1) a += __shfl_down(a, off, 64);
    a = __shfl(a, 0, 64);
    float mnew = fmaxf(mrun, a);
    float scale = __expf(mrun - mnew);
    float w = __expf(a - mnew);
    den = den*scale + w;
    #pragma unroll
    for (int i = 0; i < NI; ++i) acc[i] = acc[i]*scale + w*xl[i];
    mrun = mnew;
  }
  float dinv = 1.0f / fmaxf(den, 1e-16f);
  if constexpr (NI == 8){
    s16x8 o;
    #pragma unroll
    for (int i = 0; i < 8; ++i){
      float v = b[lane*8 + i] + acc[i]*dinv;
      o[i] = f2bf(RELU ? fmaxf(v, 0.f) : v);
    }
    *(s16x8*)((short*)hb + (size_t)n*DOUT + lane*8) = o;
  } else {
    s16x4 o;
    #pragma unroll
    for (int i = 0; i < 4; ++i){
      float v = b[lane*4 + i] + acc[i]*dinv;
      o[i] = f2bf(RELU ? fmaxf(v, 0.f) : v);
    }
    *(s16x4*)((short*)hb + (size_t)n*DOUT + lane*4) = o;
  }
}

// ---------- per-edge bilinear contraction over j (P interleaved: [node x 2cw]) ----------
__global__ void bi_k(const __hip_bfloat16* __restrict__ P, const float* __restrict__ ea,
                     const int* __restrict__ ei, const float* __restrict__ bbi,
                     __hip_bfloat16* __restrict__ bi, int kb, int kcnt){
  int cw = kcnt*ED, w2 = 2*cw;
  int g = blockIdx.x*256 + threadIdx.x;
  if (g >= N_EDGES*kcnt) return;
  int n = g / kcnt, k = g - n*kcnt;
  int src = ei[n], dst = ei[N_EDGES+n];
  const __hip_bfloat16* pl = P + (size_t)src*w2 + k*ED;
  const __hip_bfloat16* pr = P + (size_t)dst*w2 + cw + k*ED;
  const float* eap = ea + (size_t)n*ED;
  float s = 0.f;
  #pragma unroll
  for (int j = 0; j < ED; ++j)
    s += eap[j]*(__bfloat162float(pl[j]) + __bfloat162float(pr[j]));
  int kg = kb + k;
  bi[(size_t)n*KP + kg] = __float2bfloat16(s + bbi[kg]);
}

// ---------- final tiny GEMV + sigmoid ----------
__global__ void out_k(const __hip_bfloat16* __restrict__ m2, const float* __restrict__ Wm3,
                      const float* __restrict__ bm3, float* __restrict__ out){
  int n = blockIdx.x*256 + threadIdx.x;
  if (n >= N_EDGES) return;
  float acc = bm3[0];
  #pragma unroll
  for (int j = 0; j < 32; ++j) acc += __bfloat162float(m2[(size_t)n*128 + j])*Wm3[j];
  out[n] = 1.0f/(1.0f + __expf(-acc));
}

extern "C" void kernel_launch(void* const* d_in, const int* in_sizes, int n_in,
                              void* d_out, int out_size, void* d_ws, size_t ws_size,
                              hipStream_t stream) {
  const float* x   = (const float*)d_in[0];
  const float* ea  = (const float*)d_in[1];
  const int*   ei  = (const int*)d_in[2];
  const float* Wl[4]  = {(const float*)d_in[3],(const float*)d_in[8],(const float*)d_in[13],(const float*)d_in[18]};
  const float* Wr[4]  = {(const float*)d_in[4],(const float*)d_in[9],(const float*)d_in[14],(const float*)d_in[19]};
  const float* We[4]  = {(const float*)d_in[5],(const float*)d_in[10],(const float*)d_in[15],(const float*)d_in[20]};
  const float* att[4] = {(const float*)d_in[6],(const float*)d_in[11],(const float*)d_in[16],(const float*)d_in[21]};
  const float* bia[4] = {(const float*)d_in[7],(const float*)d_in[12],(const float*)d_in[17],(const float*)d_in[22]};
  const float* Wbi = (const float*)d_in[23];
  const float* bbi = (const float*)d_in[24];
  const float* Wm1 = (const float*)d_in[25];
  const float* bm1 = (const float*)d_in[26];
  const float* Wm2 = (const float*)d_in[27];
  const float* bm2 = (const float*)d_in[28];
  const float* Wm3 = (const float*)d_in[29];
  const float* bm3 = (const float*)d_in[30];
  float* out = (float*)d_out;

  char* ws = (char*)d_ws;
  size_t off = 0;
  auto alloc = [&](size_t b){ off = (off + 255) & ~(size_t)255; size_t o = off; off += b; return o; };
  size_t o_bi   = alloc((size_t)M_EDGEP*KP*2);           // 28.83 MB
  size_t o_XLXR = alloc((size_t)M_NODEP*1024*2);         // 20.71 MB
  size_t o_hb   = alloc((size_t)M_NODEP*512*2);          // 10.35 MB
  size_t o_eab  = alloc((size_t)E_AUGP*32*2);            // 3.84 MB
  size_t o_WT   = alloc((size_t)1024*512*2);             // 1.05 MB
  size_t o_WtA  = alloc((size_t)8704*512*2);             // 8.91 MB
  size_t o_WeT  = alloc((size_t)512*32*2);
  size_t o_EEP  = alloc((size_t)61440000);               // EE | P-chunk | m1,m2
  size_t o_Wm1T = alloc((size_t)384*KP*2);
  size_t o_Wm2T = alloc((size_t)128*KP*2);
  size_t o_bm1p = alloc(384*4);
  size_t o_bm2p = alloc(128*4);
  size_t o_ma   = alloc((size_t)N_NODES*ED*4);
  size_t o_cnt  = alloc(40000);
  size_t o_rp   = alloc(40004);
  size_t o_fill = alloc(40000);
  size_t o_csr  = alloc(240000);
  if (off > ws_size){
    fprintf(stderr, "kernel_launch: workspace too small: need %zu have %zu\n", off, ws_size);
    return;
  }

  float* meanat = (float*)(ws + o_ma);
  float* cntF   = (float*)(ws + o_cnt);
  int*   rowptr = (int*)(ws + o_rp);
  int*   fill   = (int*)(ws + o_fill);
  int*   csr    = (int*)(ws + o_csr);
  __hip_bfloat16* XLXR = (__hip_bfloat16*)(ws + o_XLXR);
  __hip_bfloat16* hb   = (__hip_bfloat16*)(ws + o_hb);
  __hip_bfloat16* eab  = (__hip_bfloat16*)(ws + o_eab);
  __hip_bfloat16* WT   = (__hip_bfloat16*)(ws + o_WT);
  __hip_bfloat16* WtA  = (__hip_bfloat16*)(ws + o_WtA);
  __hip_bfloat16* WeT  = (__hip_bfloat16*)(ws + o_WeT);
  __half*        EE    = (__half*)(ws + o_EEP);
  __hip_bfloat16* P    = (__hip_bfloat16*)(ws + o_EEP);
  __hip_bfloat16* Wm1T = (__hip_bfloat16*)(ws + o_Wm1T);
  __hip_bfloat16* Wm2T = (__hip_bfloat16*)(ws + o_Wm2T);
  float* bm1p = (float*)(ws + o_bm1p);
  float* bm2p = (float*)(ws + o_bm2p);
  __hip_bfloat16* bi = (__hip_bfloat16*)(ws + o_bi);
  __hip_bfloat16* m1 = (__hip_bfloat16*)(ws + o_EEP);
  __hip_bfloat16* m2 = (__hip_bfloat16*)(ws + o_EEP + 40000000);

  // mean_attr + CSR build
  hipMemsetAsync(ws + o_ma, 0, (o_cnt - o_ma) + 40000, stream);
  hipMemsetAsync(ws + o_fill, 0, 40000, stream);
  edge_attr_sum_k<<<3125, 256, 0, stream>>>(ea, ei, meanat, cntF);
  mean_div_k<<<625, 256, 0, stream>>>(meanat, cntF);
  scan_k<<<1, 1024, 0, stream>>>(cntF, rowptr);
  scatter_k<<<235, 256, 0, stream>>>(ei, rowptr, fill, csr);

  // x cast (zeroes pad rows for layer 0), ea_aug cast.
  cast_h_k<<<(M_NODEP*32 + 255)/256, 256, 0, stream>>>(x, hb, 32);
  cast_ea_k<<<(E_AUGP*32 + 255)/256, 256, 0, stream>>>(ea, meanat, eab);

  const int dins[4]  = {32, 256, 512, 512};
  const int douts[4] = {256, 512, 512, 512};
  for (int L = 0; L < 4; ++L){
    int din = dins[L], dn = douts[L];
    transpose_wlr_k<<<(2*din*dn + 255)/256, 256, 0, stream>>>(Wl[L], Wr[L], WT, din, dn);
    weT_k<<<(dn*32 + 255)/256, 256, 0, stream>>>(We[L], WeT, dn);
    dim3 g1(M_NODEP/128, 2*dn/128);
    mfma_gemm_k<__hip_bfloat16,false,false><<<g1, 256, 0, stream>>>(
        hb, WT, XLXR, nullptr, N_NODES, din, din, din, 2*dn);
    dim3 ge(E_AUGP/128, dn/128);
    mfma_gemm_k<__half,false,false><<<ge, 256, 0, stream>>>(eab, WeT, EE, nullptr, E_AUG, 32, 32, 32, dn);
    if (dn == 256)
      gat_fused_k<256,true><<<2500, 256, 0, stream>>>(XLXR, EE, ei, rowptr, csr, att[L], bia[L], hb);
    else if (L == 3)
      gat_fused_k<512,false><<<2500, 256, 0, stream>>>(XLXR, EE, ei, rowptr, csr, att[L], bia[L], hb);
    else
      gat_fused_k<512,true><<<2500, 256, 0, stream>>>(XLXR, EE, ei, rowptr, csr, att[L], bia[L], hb);
  }
  // hb holds final node embeddings [M_NODEP x 512] bf16

  wbi_transpose_k<<<(BI_OUT*1024*ED + 255)/256, 256, 0, stream>>>(Wbi, WtA);

  // merged PL|PR GEMM per chunk: N = 2*cw, then bilinear
  const int kbs[3]   = {0, 96, 192};
  const int kcnts[3] = {96, 96, 80};
  const int bases[3] = {0, 3072, 6144};
  for (int c = 0; c < 3; ++c){
    int cw = kcnts[c]*ED, w2 = 2*cw;
    dim3 gp(M_NODEP/128, w2/128);
    mfma_gemm_k<__hip_bfloat16,false,false><<<gp, 256, 0, stream>>>(
        hb, WtA + (size_t)bases[c]*512, P, nullptr, N_NODES, 512, 512, 512, w2);
    bi_k<<<(N_EDGES*kcnts[c] + 255)/256, 256, 0, stream>>>(P, ea, ei, bbi, bi, kbs[c], kcnts[c]);
  }

  prep_mlp_k<<<(384*KP + 255)/256, 256, 0, stream>>>(Wm1, bm1, Wm2, bm2, Wm1T, Wm2T, bm1p, bm2p);
  dim3 gm1(M_EDGEP/128, 3);
  mfma_gemm_k<__hip_bfloat16,true,true><<<gm1, 256, 0, stream>>>(bi, Wm1T, m1, bm1p, M_EDGEP, KP, KP, KP, 384);
  dim3 gm2(M_EDGEP/128, 1);
  mfma_gemm_k<__hip_bfloat16,true,true><<<gm2, 256, 0, stream>>>(m1, Wm2T, m2, bm2p, M_EDGEP, KP, 384, KP, 128);
  out_k<<<(N_EDGES + 255)/256, 256, 0, stream>>>(m2, Wm3, bm3, out);
}